// Round 3
// baseline (403.806 us; speedup 1.0000x reference)
//
#include <hip/hip_runtime.h>
#include <math.h>

#define N_ 4096
#define F_ 128
#define D_ 64
#define KH_ 3
#define ZS_ 8              // K-split for agemm
#define KC_ (N_ / ZS_)     // 512 columns per z-slice

// workspace layout (float offsets)
#define OFF_E      0                          // N*D           = 262144
#define OFF_XW     (N_*D_)                    // KH*N*D        = 786432
#define OFF_SE     (OFF_XW + KH_*N_*D_)       // D             = 64
#define OFF_T      (OFF_SE + D_)              // KH*D*D        = 12288
#define OFF_DVEC   (OFF_T + KH_*D_*D_)        // KH*N          = 12288
#define OFF_YT     (OFF_DVEC + KH_*N_)        // KH*D*N bf16   = 393216 floats
#define OFF_AYP    (OFF_YT + KH_*D_*N_/2)     // ZS*KH*N*D     = 6291456
// total ~ 7.76M floats = 31 MB

typedef __attribute__((ext_vector_type(8))) short bf16x8;
typedef __attribute__((ext_vector_type(4))) float f32x4;

static __device__ __forceinline__ unsigned short f2bf(float f) {
  union { float f; unsigned u; } v; v.f = f;
  unsigned r = (v.u + 0x7fffu + ((v.u >> 16) & 1u)) >> 16;
  return (unsigned short)r;
}

// ---------------- proj: E = X@W_emb, XW[k] = X@W_hops[k] ----------------
__global__ __launch_bounds__(256) void proj_kernel(
    const float* __restrict__ X, const float* __restrict__ W_emb,
    const float* __restrict__ W_hops, float* __restrict__ ws)
{
  __shared__ __align__(16) float sXT[32][68];  // [f][i]
  __shared__ __align__(16) float sW[32][68];   // [f][d]
  const int t = threadIdx.x;
  const int m = blockIdx.y;            // 0 -> E, 1..3 -> XW[m-1]
  const int row0 = blockIdx.x * 64;
  const float* W = (m == 0) ? W_emb : (W_hops + (size_t)(m - 1) * F_ * D_);
  float* out = (m == 0) ? (ws + OFF_E) : (ws + OFF_XW + (size_t)(m - 1) * N_ * D_);
  const int tx = t & 15, ty = t >> 4;
  const int d0 = tx * 4, i0 = ty * 4;
  float acc[4][4] = {};
  for (int fc = 0; fc < F_; fc += 32) {
    {
      int i_l = t >> 3;               // 0..31
      int f_l = (t & 7) * 4;          // 0..28
      for (int r = 0; r < 2; ++r) {
        int i = i_l + r * 32;
        float4 v = *(const float4*)(X + (size_t)(row0 + i) * F_ + fc + f_l);
        sXT[f_l + 0][i] = v.x; sXT[f_l + 1][i] = v.y;
        sXT[f_l + 2][i] = v.z; sXT[f_l + 3][i] = v.w;
      }
      int f2 = t >> 4;                // 0..15
      int d  = (t & 15) * 4;
      for (int r = 0; r < 2; ++r) {
        int f = f2 + r * 16;
        *(float4*)&sW[f][d] = *(const float4*)(W + (size_t)(fc + f) * D_ + d);
      }
    }
    __syncthreads();
#pragma unroll 8
    for (int f = 0; f < 32; ++f) {
      float a[4], b[4];
      *(float4*)a = *(const float4*)&sXT[f][i0];
      *(float4*)b = *(const float4*)&sW[f][d0];
      for (int x = 0; x < 4; ++x)
        for (int y = 0; y < 4; ++y)
          acc[x][y] += a[x] * b[y];
    }
    __syncthreads();
  }
  for (int x = 0; x < 4; ++x)
    *(float4*)(out + (size_t)(row0 + i0 + x) * D_ + d0) = *(float4*)acc[x];
}

// ---------------- colsum: S[d] = sum_i E[i][d] ----------------
__global__ __launch_bounds__(256) void colsum_kernel(
    const float* __restrict__ E, float* __restrict__ S)
{
  int t = threadIdx.x;
  int d = t & 63;
  int sub = t >> 6;
  int i0 = blockIdx.x * 64;
  float acc = 0.f;
  for (int i = i0 + sub; i < i0 + 64; i += 4)
    acc += E[(size_t)i * D_ + d];
  atomicAdd(&S[d], acc);
}

// ---------------- degree: dvec[k][i] = (rowsum(A_k)_i + alpha*E_i.S)^-1/2 ----
__global__ __launch_bounds__(256) void degree_kernel(
    const float* __restrict__ A, const float* __restrict__ E,
    const float* __restrict__ S, const float* __restrict__ alpha_p,
    float* __restrict__ dvec)
{
  int lane = threadIdx.x & 63;
  int wave = threadIdx.x >> 6;
  int row = blockIdx.x * 4 + wave;     // 0..KH*N-1
  int i = row & (N_ - 1);
  const float4* Ar = (const float4*)(A + (size_t)row * N_);
  float s = 0.f;
#pragma unroll
  for (int it = 0; it < 16; ++it) {
    float4 v = Ar[lane + it * 64];
    s += (v.x + v.y) + (v.z + v.w);
  }
  float alpha = *alpha_p;
  s += alpha * E[(size_t)i * D_ + lane] * S[lane];
#pragma unroll
  for (int off = 32; off > 0; off >>= 1)
    s += __shfl_xor(s, off);
  if (lane == 0) dvec[row] = 1.0f / sqrtf(s);
}

// ---------------- yprep: Yt[k][n][j] = bf16( dvec[k][j] * XW[k][j][n] ) -----
__global__ __launch_bounds__(256) void yprep_kernel(float* __restrict__ ws)
{
  const int k = blockIdx.y;
  const int j0 = blockIdx.x * 64;
  const float* XWk = ws + OFF_XW + (size_t)k * N_ * D_;
  const float* dk  = ws + OFF_DVEC + (size_t)k * N_;
  unsigned short* Ytk = (unsigned short*)(ws + OFF_YT) + (size_t)k * D_ * N_;
  __shared__ float sT[64][65];         // [n][j]
  int t = threadIdx.x;
  {
    int j = t >> 2;                    // 0..63
    int c0 = (t & 3) * 16;
    float dv = dk[j0 + j];
    for (int r = 0; r < 4; ++r) {
      float4 v = *(const float4*)(XWk + (size_t)(j0 + j) * D_ + c0 + 4 * r);
      sT[c0 + 4 * r + 0][j] = v.x * dv;
      sT[c0 + 4 * r + 1][j] = v.y * dv;
      sT[c0 + 4 * r + 2][j] = v.z * dv;
      sT[c0 + 4 * r + 3][j] = v.w * dv;
    }
  }
  __syncthreads();
  {
    int n = t >> 2;                    // 0..63
    int jq = (t & 3) * 16;
    __align__(16) unsigned short buf[16];
#pragma unroll
    for (int i = 0; i < 16; ++i) buf[i] = f2bf(sT[n][jq + i]);
    uint4* dst = (uint4*)(Ytk + (size_t)n * N_ + j0 + jq);
    dst[0] = *(uint4*)&buf[0];
    dst[1] = *(uint4*)&buf[8];
  }
}

// ---------------- T_k = E^T @ (d_k ⊙ XW_k), 64x64 each ----------------
__global__ __launch_bounds__(256) void tmat_kernel(
    const float* __restrict__ ws, float* __restrict__ T)
{
  const float* E   = ws + OFF_E;
  const float* XWk = ws + OFF_XW + (size_t)blockIdx.y * N_ * D_;
  const float* dk  = ws + OFF_DVEC + (size_t)blockIdx.y * N_;
  __shared__ __align__(16) float sE[32][68];
  __shared__ __align__(16) float sY[32][68];
  int t = threadIdx.x;
  int tx = t & 15, ty = t >> 4;
  int d0 = tx * 4, c0 = ty * 4;
  float acc[4][4] = {};
  int base0 = blockIdx.x * 128;        // 32 x-blocks
  for (int sub = 0; sub < 4; ++sub) {
    int base = base0 + sub * 32;
    {
      int i_l = t >> 3;               // 0..31
      int c   = (t & 7) * 4;          // 0..28
      float dv = dk[base + i_l];
      for (int r = 0; r < 2; ++r) {
        int col = c + r * 32;
        *(float4*)&sE[i_l][col] = *(const float4*)(E + (size_t)(base + i_l) * D_ + col);
        float4 y = *(const float4*)(XWk + (size_t)(base + i_l) * D_ + col);
        y.x *= dv; y.y *= dv; y.z *= dv; y.w *= dv;
        *(float4*)&sY[i_l][col] = y;
      }
    }
    __syncthreads();
#pragma unroll 8
    for (int i = 0; i < 32; ++i) {
      float c4[4], y4[4];
      *(float4*)c4 = *(const float4*)&sE[i][c0];
      *(float4*)y4 = *(const float4*)&sY[i][d0];
      for (int a = 0; a < 4; ++a)
        for (int b = 0; b < 4; ++b)
          acc[a][b] += c4[a] * y4[b];
    }
    __syncthreads();
  }
  float* Tk = T + (size_t)blockIdx.y * D_ * D_;
  for (int a = 0; a < 4; ++a)
    for (int b = 0; b < 4; ++b)
      atomicAdd(&Tk[(c0 + a) * D_ + d0 + b], acc[a][b]);
}

// ---------------- main GEMM (MFMA bf16, LDS-free): --------------------------
// AYp[z][k] = A_k[:, kz] @ Y_k[kz].  Fragments loaded directly from global:
// A in fp32 (converted to bf16 in regs), B from Yt (bf16, L2-resident).
// Hop/row order reversed so the 2nd pass over A starts where degree ended
// (Infinity-Cache recency).
__global__ __launch_bounds__(256) void agemm_kernel(
    const float* __restrict__ A, const float* __restrict__ ws,
    float* __restrict__ AYp)
{
  const int k = KH_ - 1 - blockIdx.y;                  // reversed hop
  const int row0 = (gridDim.x - 1 - blockIdx.x) * 64;  // reversed rows
  const int kz0 = blockIdx.z * KC_;
  const float* Ak = A + ((size_t)k << 24);
  const unsigned short* Ytk = (const unsigned short*)(ws + OFF_YT) + (size_t)k * D_ * N_;

  const int t = threadIdx.x;
  const int lane = t & 63;
  const int w = t >> 6;                // wave 0..3 -> rows w*16..w*16+15
  const int m = lane & 15;             // A row / B col within 16
  const int q = lane >> 4;             // k-chunk 0..3 (k = q*8 + j)

  f32x4 acc[4];
#pragma unroll
  for (int i = 0; i < 4; ++i) acc[i] = (f32x4){0.f, 0.f, 0.f, 0.f};

  const float* aRow = Ak + (size_t)(row0 + w * 16 + m) * N_ + kz0 + q * 8;
  const unsigned short* yBase = Ytk + kz0 + q * 8;

#pragma unroll 4
  for (int kt = 0; kt < KC_; kt += 32) {
    float4 a0 = *(const float4*)(aRow + kt);
    float4 a1 = *(const float4*)(aRow + kt + 4);
    bf16x8 af;
    af[0] = (short)f2bf(a0.x); af[1] = (short)f2bf(a0.y);
    af[2] = (short)f2bf(a0.z); af[3] = (short)f2bf(a0.w);
    af[4] = (short)f2bf(a1.x); af[5] = (short)f2bf(a1.y);
    af[6] = (short)f2bf(a1.z); af[7] = (short)f2bf(a1.w);
#pragma unroll
    for (int nt = 0; nt < 4; ++nt) {
      bf16x8 bfv = *(const bf16x8*)(yBase + (size_t)(nt * 16 + m) * N_ + kt);
      acc[nt] = __builtin_amdgcn_mfma_f32_16x16x32_bf16(af, bfv, acc[nt], 0, 0, 0);
    }
  }
  // C/D layout: col = lane&15 (B n-index), row = q*4 + reg (A m-index)
  float* outp = AYp + (((size_t)blockIdx.z * KH_ + k) * N_ + row0 + w * 16) * D_;
#pragma unroll
  for (int nt = 0; nt < 4; ++nt)
#pragma unroll
    for (int r = 0; r < 4; ++r)
      outp[(size_t)(q * 4 + r) * D_ + nt * 16 + m] = acc[nt][r];
}

// ---------------- epilogue: out = relu(sum_k d_i*(AY + alpha*E@T_k)) -------
__global__ __launch_bounds__(256) void epilogue_kernel(
    const float* __restrict__ ws, const float* __restrict__ alpha_p,
    float* __restrict__ out)
{
  int g = blockIdx.x * 256 + threadIdx.x;
  int i = g >> 6, d = g & 63;
  const float* E    = ws + OFF_E;
  const float* T    = ws + OFF_T;
  const float* dvec = ws + OFF_DVEC;
  const float* AYp  = ws + OFF_AYP;
  float alpha = *alpha_p;
  float s = 0.f;
  for (int k = 0; k < KH_; ++k) {
    float ay = 0.f;
#pragma unroll
    for (int jc = 0; jc < ZS_; ++jc)
      ay += AYp[(((size_t)jc * KH_ + k) * N_ + i) * D_ + d];
    float lr = 0.f;
    const float* Tk = T + k * D_ * D_;
#pragma unroll 16
    for (int c = 0; c < D_; ++c)
      lr += E[(size_t)i * D_ + c] * Tk[c * D_ + d];
    s += dvec[k * N_ + i] * (ay + alpha * lr);
  }
  out[g] = fmaxf(s, 0.f);
}

extern "C" void kernel_launch(void* const* d_in, const int* in_sizes, int n_in,
                              void* d_out, int out_size, void* d_ws, size_t ws_size,
                              hipStream_t stream) {
  const float* X      = (const float*)d_in[0];
  const float* A      = (const float*)d_in[1];
  const float* W_emb  = (const float*)d_in[2];
  const float* W_hops = (const float*)d_in[3];
  const float* alpha_p= (const float*)d_in[4];
  float* out = (float*)d_out;
  float* ws  = (float*)d_ws;

  // zero S_E and T (accumulated via atomics) — contiguous region
  hipMemsetAsync(ws + OFF_SE, 0, (D_ + KH_ * D_ * D_) * sizeof(float), stream);

  proj_kernel<<<dim3(N_ / 64, 4), 256, 0, stream>>>(X, W_emb, W_hops, ws);
  colsum_kernel<<<dim3(N_ / 64), 256, 0, stream>>>(ws + OFF_E, ws + OFF_SE);
  degree_kernel<<<dim3(KH_ * N_ / 4), 256, 0, stream>>>(A, ws + OFF_E, ws + OFF_SE,
                                                        alpha_p, ws + OFF_DVEC);
  yprep_kernel<<<dim3(N_ / 64, KH_), 256, 0, stream>>>(ws);
  tmat_kernel<<<dim3(32, KH_), 256, 0, stream>>>(ws, ws + OFF_T);
  agemm_kernel<<<dim3(N_ / 64, KH_, ZS_), 256, 0, stream>>>(A, ws, ws + OFF_AYP);
  epilogue_kernel<<<dim3(N_ * D_ / 256), 256, 0, stream>>>(ws, alpha_p, out);
}

// Round 4
// 357.476 us; speedup vs baseline: 1.1296x; 1.1296x over previous
//
#include <hip/hip_runtime.h>
#include <math.h>

#define N_ 4096
#define F_ 128
#define D_ 64
#define KH_ 3
#define ZS_ 4              // K-split for agemm
#define KC_ (N_ / ZS_)     // 1024 columns per z-slice

// workspace layout (float offsets)
#define OFF_E      0                          // N*D           = 262144
#define OFF_XW     (N_*D_)                    // KH*N*D        = 786432
#define OFF_SE     (OFF_XW + KH_*N_*D_)       // D             = 64
#define OFF_T      (OFF_SE + D_)              // KH*D*D        = 12288
#define OFF_DVEC   (OFF_T + KH_*D_*D_)        // KH*N          = 12288
#define OFF_YT     (OFF_DVEC + KH_*N_)        // KH*D*N bf16   = 393216 floats
#define OFF_AYP    (OFF_YT + KH_*D_*N_/2)     // ZS*KH*N*D     = 3145728
// total ~ 4.6M floats = 18.5 MB

typedef __attribute__((ext_vector_type(8))) short bf16x8;
typedef __attribute__((ext_vector_type(4))) float f32x4;

static __device__ __forceinline__ unsigned short f2bf(float f) {
  union { float f; unsigned u; } v; v.f = f;
  unsigned r = (v.u + 0x7fffu + ((v.u >> 16) & 1u)) >> 16;
  return (unsigned short)r;
}

// ------- proj: E = X@W_emb, XW[k] = X@W_hops[k]; fused colsum(E) -> S ------
__global__ __launch_bounds__(256) void proj_kernel(
    const float* __restrict__ X, const float* __restrict__ W_emb,
    const float* __restrict__ W_hops, float* __restrict__ ws)
{
  __shared__ __align__(16) float sXT[32][68];  // [f][i]
  __shared__ __align__(16) float sW[32][68];   // [f][d]
  const int t = threadIdx.x;
  const int m = blockIdx.y;            // 0 -> E, 1..3 -> XW[m-1]
  const int row0 = blockIdx.x * 64;
  const float* W = (m == 0) ? W_emb : (W_hops + (size_t)(m - 1) * F_ * D_);
  float* out = (m == 0) ? (ws + OFF_E) : (ws + OFF_XW + (size_t)(m - 1) * N_ * D_);
  const int tx = t & 15, ty = t >> 4;
  const int d0 = tx * 4, i0 = ty * 4;
  float acc[4][4] = {};
  for (int fc = 0; fc < F_; fc += 32) {
    {
      int i_l = t >> 3;               // 0..31
      int f_l = (t & 7) * 4;          // 0..28
      for (int r = 0; r < 2; ++r) {
        int i = i_l + r * 32;
        float4 v = *(const float4*)(X + (size_t)(row0 + i) * F_ + fc + f_l);
        sXT[f_l + 0][i] = v.x; sXT[f_l + 1][i] = v.y;
        sXT[f_l + 2][i] = v.z; sXT[f_l + 3][i] = v.w;
      }
      int f2 = t >> 4;                // 0..15
      int d  = (t & 15) * 4;
      for (int r = 0; r < 2; ++r) {
        int f = f2 + r * 16;
        *(float4*)&sW[f][d] = *(const float4*)(W + (size_t)(fc + f) * D_ + d);
      }
    }
    __syncthreads();
#pragma unroll 8
    for (int f = 0; f < 32; ++f) {
      float a[4], b[4];
      *(float4*)a = *(const float4*)&sXT[f][i0];
      *(float4*)b = *(const float4*)&sW[f][d0];
      for (int x = 0; x < 4; ++x)
        for (int y = 0; y < 4; ++y)
          acc[x][y] += a[x] * b[y];
    }
    __syncthreads();
  }
  for (int x = 0; x < 4; ++x)
    *(float4*)(out + (size_t)(row0 + i0 + x) * D_ + d0) = *(float4*)acc[x];
  if (m == 0) {
    // fused column-sum of this E tile -> S (atomics; S pre-zeroed)
    float p[4];
    for (int y = 0; y < 4; ++y)
      p[y] = acc[0][y] + acc[1][y] + acc[2][y] + acc[3][y];
    *(float4*)&sXT[ty][d0] = *(float4*)p;     // rows 0..15, cols 0..63
    __syncthreads();
    if (ty < 4) {
      int c = ty * 16 + tx;
      float s = 0.f;
#pragma unroll
      for (int r = 0; r < 16; ++r) s += sXT[r][c];
      atomicAdd(ws + OFF_SE + c, s);
    }
  }
}

// ---------------- degree: dvec[k][i] = (rowsum(A_k)_i + alpha*E_i.S)^-1/2 ----
__global__ __launch_bounds__(256) void degree_kernel(
    const float* __restrict__ A, const float* __restrict__ E,
    const float* __restrict__ S, const float* __restrict__ alpha_p,
    float* __restrict__ dvec)
{
  int lane = threadIdx.x & 63;
  int wave = threadIdx.x >> 6;
  int row = blockIdx.x * 4 + wave;     // 0..KH*N-1
  int i = row & (N_ - 1);
  const float4* Ar = (const float4*)(A + (size_t)row * N_);
  float s = 0.f;
#pragma unroll
  for (int it = 0; it < 16; ++it) {
    float4 v = Ar[lane + it * 64];
    s += (v.x + v.y) + (v.z + v.w);
  }
  float alpha = *alpha_p;
  s += alpha * E[(size_t)i * D_ + lane] * S[lane];
#pragma unroll
  for (int off = 32; off > 0; off >>= 1)
    s += __shfl_xor(s, off);
  if (lane == 0) dvec[row] = 1.0f / sqrtf(s);
}

// ------- prep (merged): x<64 -> yprep block; x>=64 -> tmat block ----------
// yprep: Yt[k][n][j] = bf16( dvec[k][j] * XW[k][j][n] )
// tmat : T_k += E^T @ (d_k ⊙ XW_k)  (64x64, atomics; T pre-zeroed)
__global__ __launch_bounds__(256) void prep_kernel(float* __restrict__ ws,
                                                   float* __restrict__ T)
{
  const int k = blockIdx.y;
  const float* XWk = ws + OFF_XW + (size_t)k * N_ * D_;
  const float* dk  = ws + OFF_DVEC + (size_t)k * N_;
  int t = threadIdx.x;

  if (blockIdx.x < 64) {
    // ---------------- yprep role ----------------
    const int j0 = blockIdx.x * 64;
    unsigned short* Ytk = (unsigned short*)(ws + OFF_YT) + (size_t)k * D_ * N_;
    __shared__ float sT[64][65];         // [n][j]
    {
      int j = t >> 2;                    // 0..63
      int c0 = (t & 3) * 16;
      float dv = dk[j0 + j];
      for (int r = 0; r < 4; ++r) {
        float4 v = *(const float4*)(XWk + (size_t)(j0 + j) * D_ + c0 + 4 * r);
        sT[c0 + 4 * r + 0][j] = v.x * dv;
        sT[c0 + 4 * r + 1][j] = v.y * dv;
        sT[c0 + 4 * r + 2][j] = v.z * dv;
        sT[c0 + 4 * r + 3][j] = v.w * dv;
      }
    }
    __syncthreads();
    {
      int n = t >> 2;                    // 0..63
      int jq = (t & 3) * 16;
      __align__(16) unsigned short buf[16];
#pragma unroll
      for (int i = 0; i < 16; ++i) buf[i] = f2bf(sT[n][jq + i]);
      uint4* dst = (uint4*)(Ytk + (size_t)n * N_ + j0 + jq);
      dst[0] = *(uint4*)&buf[0];
      dst[1] = *(uint4*)&buf[8];
    }
  } else {
    // ---------------- tmat role ----------------
    const float* E = ws + OFF_E;
    __shared__ __align__(16) float sE[32][68];
    __shared__ __align__(16) float sY[32][68];
    int tx = t & 15, ty = t >> 4;
    int d0 = tx * 4, c0 = ty * 4;
    float acc[4][4] = {};
    int base0 = (blockIdx.x - 64) * 128;   // 32 blocks x 128 rows
    for (int sub = 0; sub < 4; ++sub) {
      int base = base0 + sub * 32;
      {
        int i_l = t >> 3;               // 0..31
        int c   = (t & 7) * 4;          // 0..28
        float dv = dk[base + i_l];
        for (int r = 0; r < 2; ++r) {
          int col = c + r * 32;
          *(float4*)&sE[i_l][col] = *(const float4*)(E + (size_t)(base + i_l) * D_ + col);
          float4 y = *(const float4*)(XWk + (size_t)(base + i_l) * D_ + col);
          y.x *= dv; y.y *= dv; y.z *= dv; y.w *= dv;
          *(float4*)&sY[i_l][col] = y;
        }
      }
      __syncthreads();
#pragma unroll 8
      for (int i = 0; i < 32; ++i) {
        float c4[4], y4[4];
        *(float4*)c4 = *(const float4*)&sE[i][c0];
        *(float4*)y4 = *(const float4*)&sY[i][d0];
        for (int a = 0; a < 4; ++a)
          for (int b = 0; b < 4; ++b)
            acc[a][b] += c4[a] * y4[b];
      }
      __syncthreads();
    }
    float* Tk = T + (size_t)k * D_ * D_;
    for (int a = 0; a < 4; ++a)
      for (int b = 0; b < 4; ++b)
        atomicAdd(&Tk[(c0 + a) * D_ + d0 + b], acc[a][b]);
  }
}

// ---------------- main GEMM (MFMA bf16): AYp[z][k] = A_k[:,kz] @ Y_k[kz] ----
__global__ __launch_bounds__(256) void agemm_kernel(
    const float* __restrict__ A, const float* __restrict__ ws,
    float* __restrict__ AYp)
{
  const int k = blockIdx.y;
  const int row0 = blockIdx.x * 64;
  const int kz0 = blockIdx.z * KC_;
  const float* Ak = A + ((size_t)k << 24);
  const unsigned short* Ytk = (const unsigned short*)(ws + OFF_YT) + (size_t)k * D_ * N_;

  __shared__ __align__(16) unsigned short sA[64][72];  // [row][k] bf16, +8 pad
  __shared__ __align__(16) unsigned short sY[64][72];  // [n][k]   bf16, +8 pad

  const int t = threadIdx.x;
  const int lane = t & 63;
  const int w = t >> 6;                // wave 0..3 -> rows w*16..w*16+15
  const int m = lane & 15;
  const int q = lane >> 4;             // 0..3

  f32x4 acc[4];
#pragma unroll
  for (int i = 0; i < 4; ++i) acc[i] = (f32x4){0.f, 0.f, 0.f, 0.f};

  const int ar  = t >> 2;              // 0..63 (row / n)
  const int akq = (t & 3) * 16;        // 0,16,32,48

  for (int kt = 0; kt < KC_; kt += 64) {
    // stage A tile: 64 rows x 64 k fp32 -> bf16
    {
      const float* gA = Ak + (size_t)(row0 + ar) * N_ + kz0 + kt + akq;
#pragma unroll
      for (int r = 0; r < 4; ++r) {
        float4 v = *(const float4*)(gA + 4 * r);
        ushort4 u;
        u.x = f2bf(v.x); u.y = f2bf(v.y); u.z = f2bf(v.z); u.w = f2bf(v.w);
        *(ushort4*)&sA[ar][akq + 4 * r] = u;
      }
      // stage Y tile: 64 n x 64 k bf16 (already bf16 in Yt)
      const uint4* gY = (const uint4*)(Ytk + (size_t)ar * N_ + kz0 + kt + akq);
      *(uint4*)&sY[ar][akq + 0] = gY[0];
      *(uint4*)&sY[ar][akq + 8] = gY[1];
    }
    __syncthreads();
    const int mrow = w * 16 + m;
#pragma unroll
    for (int s = 0; s < 2; ++s) {
      bf16x8 af = *(const bf16x8*)&sA[mrow][s * 32 + q * 8];
#pragma unroll
      for (int nt = 0; nt < 4; ++nt) {
        bf16x8 bfv = *(const bf16x8*)&sY[nt * 16 + m][s * 32 + q * 8];
        acc[nt] = __builtin_amdgcn_mfma_f32_16x16x32_bf16(af, bfv, acc[nt], 0, 0, 0);
      }
    }
    __syncthreads();
  }
  // C/D layout: col = lane&15, row = q*4 + reg
  float* outp = AYp + (((size_t)blockIdx.z * KH_ + k) * N_ + row0 + w * 16) * D_;
#pragma unroll
  for (int nt = 0; nt < 4; ++nt)
#pragma unroll
    for (int r = 0; r < 4; ++r)
      outp[(size_t)(q * 4 + r) * D_ + nt * 16 + m] = acc[nt][r];
}

// ---------------- epilogue: out = relu(sum_k d_i*(AY + alpha*E@T_k)) -------
__global__ __launch_bounds__(256) void epilogue_kernel(
    const float* __restrict__ ws, const float* __restrict__ alpha_p,
    float* __restrict__ out)
{
  int g = blockIdx.x * 256 + threadIdx.x;
  int i = g >> 6, d = g & 63;
  const float* E    = ws + OFF_E;
  const float* T    = ws + OFF_T;
  const float* dvec = ws + OFF_DVEC;
  const float* AYp  = ws + OFF_AYP;
  float alpha = *alpha_p;
  float s = 0.f;
  for (int k = 0; k < KH_; ++k) {
    float ay = 0.f;
#pragma unroll
    for (int jc = 0; jc < ZS_; ++jc)
      ay += AYp[(((size_t)jc * KH_ + k) * N_ + i) * D_ + d];
    float lr = 0.f;
    const float* Tk = T + k * D_ * D_;
#pragma unroll 16
    for (int c = 0; c < D_; ++c)
      lr += E[(size_t)i * D_ + c] * Tk[c * D_ + d];
    s += dvec[k * N_ + i] * (ay + alpha * lr);
  }
  out[g] = fmaxf(s, 0.f);
}

extern "C" void kernel_launch(void* const* d_in, const int* in_sizes, int n_in,
                              void* d_out, int out_size, void* d_ws, size_t ws_size,
                              hipStream_t stream) {
  const float* X      = (const float*)d_in[0];
  const float* A      = (const float*)d_in[1];
  const float* W_emb  = (const float*)d_in[2];
  const float* W_hops = (const float*)d_in[3];
  const float* alpha_p= (const float*)d_in[4];
  float* out = (float*)d_out;
  float* ws  = (float*)d_ws;

  // zero S_E and T (accumulated via atomics) — contiguous region
  hipMemsetAsync(ws + OFF_SE, 0, (D_ + KH_ * D_ * D_) * sizeof(float), stream);

  proj_kernel<<<dim3(N_ / 64, 4), 256, 0, stream>>>(X, W_emb, W_hops, ws);
  degree_kernel<<<dim3(KH_ * N_ / 4), 256, 0, stream>>>(A, ws + OFF_E, ws + OFF_SE,
                                                        alpha_p, ws + OFF_DVEC);
  prep_kernel<<<dim3(96, KH_), 256, 0, stream>>>(ws, ws + OFF_T);
  agemm_kernel<<<dim3(N_ / 64, KH_, ZS_), 256, 0, stream>>>(A, ws, ws + OFF_AYP);
  epilogue_kernel<<<dim3(N_ * D_ / 256), 256, 0, stream>>>(ws, alpha_p, out);
}